// Round 2
// baseline (2315.976 us; speedup 1.0000x reference)
//
#include <hip/hip_runtime.h>
#include <hip/hip_bf16.h>
#include <math.h>

#define BB 2
#define SS 1024
#define DD 768
#define HH 12
#define DHH 64
#define LL 4
#define VV 32000
#define FF 3072
#define MR (BB*SS)   // 2048 rows

typedef unsigned short u16;
typedef unsigned int u32;
typedef __hip_bfloat16 bf16;

using f32x4  = __attribute__((ext_vector_type(4))) float;
using bf16x8 = __attribute__((ext_vector_type(8))) short;   // 8 bf16 in 4 VGPRs

__device__ inline u16 f2b(float f) {
    union { bf16 h; u16 u; } c; c.h = __float2bfloat16(f); return c.u;
}
__device__ inline float b2f(u16 u) {
    union { u16 u; bf16 h; } c; c.u = u; return __bfloat162float(c.h);
}

template<bool BF>
__device__ inline float ldg_t(const void* p, size_t i) {
    if (BF) return b2f(((const u16*)p)[i]);
    else    return ((const float*)p)[i];
}

// bijective XCD-aware block swizzle (m204): HW round-robins blockIdx%8 across
// XCDs; remap so each XCD computes a contiguous chunk of tiles.
__device__ inline int xcd_swizzle(int orig, int nwg) {
    int q = nwg >> 3, r = nwg & 7;
    int xcd = orig & 7, pos = orig >> 3;
    return (xcd < r ? xcd * (q + 1) : r * (q + 1) + (xcd - r) * q) + pos;
}

// ---------------- dtype detect: ln1_g is all ones ----------------
__global__ void detect_kernel(const unsigned* __restrict__ ln1g, int* __restrict__ flag) {
    *flag = (ln1g[0] == 0x3F803F80u) ? 1 : 0;   // bf16 ones pair vs f32 one
}

// ---------------- embedding + positional encoding (x stays f32) ----------------
template<bool BF>
__device__ void embed_body(const int* tokens, const void* tok_emb, float* x) {
    int row = blockIdx.x;            // b*S + s
    int s = row & (SS - 1);
    int tok = tokens[row];
    const float scale = 27.712812921102035f;   // sqrt(768)
    for (int d = threadIdx.x; d < DD; d += 256) {
        float val = ldg_t<BF>(tok_emb, (size_t)tok * DD + d) * scale;
        int i2 = d & ~1;
        float freq = expf(-9.210340371976184f * (float)i2 / (float)DD);
        float arg = (float)s * freq;
        val += (d & 1) ? cosf(arg) : sinf(arg);
        x[(size_t)row * DD + d] = val;
    }
}
__global__ __launch_bounds__(256) void embed_kernel(
    const int* __restrict__ flag, const int* __restrict__ tokens,
    const void* __restrict__ tok_emb, float* __restrict__ x)
{
    if (*flag) embed_body<true>(tokens, tok_emb, x);
    else       embed_body<false>(tokens, tok_emb, x);
}

// ---------------- layernorm (row of 768), f32 in -> bf16 out ----------------
template<bool BF>
__device__ void ln_body(const float* x, const void* g, size_t goff,
                        const void* bta, size_t boff, u16* out,
                        float* rs, float* rq) {
    int row = blockIdx.x;
    const float* xr = x + (size_t)row * DD;
    int t = threadIdx.x;
    float v0 = xr[t], v1 = xr[t + 256], v2 = xr[t + 512];
    float s = v0 + v1 + v2;
    float sq = v0 * v0 + v1 * v1 + v2 * v2;
    for (int off = 32; off; off >>= 1) { s += __shfl_xor(s, off); sq += __shfl_xor(sq, off); }
    int wave = t >> 6, lane = t & 63;
    if (lane == 0) { rs[wave] = s; rq[wave] = sq; }
    __syncthreads();
    s = rs[0] + rs[1] + rs[2] + rs[3];
    sq = rq[0] + rq[1] + rq[2] + rq[3];
    float mu = s * (1.0f / DD);
    float var = sq * (1.0f / DD) - mu * mu;
    float rstd = rsqrtf(var + 1e-5f);
    u16* orow = out + (size_t)row * DD;
    orow[t]       = f2b((v0 - mu) * rstd * ldg_t<BF>(g, goff + t)       + ldg_t<BF>(bta, boff + t));
    orow[t + 256] = f2b((v1 - mu) * rstd * ldg_t<BF>(g, goff + t + 256) + ldg_t<BF>(bta, boff + t + 256));
    orow[t + 512] = f2b((v2 - mu) * rstd * ldg_t<BF>(g, goff + t + 512) + ldg_t<BF>(bta, boff + t + 512));
}
__global__ __launch_bounds__(256) void ln_kernel(
    const int* __restrict__ flag, const float* __restrict__ x,
    const void* __restrict__ g, size_t goff,
    const void* __restrict__ bta, size_t boff, u16* __restrict__ out)
{
    __shared__ float rs[4], rq[4];
    if (*flag) ln_body<true>(x, g, goff, bta, boff, out, rs, rq);
    else       ln_body<false>(x, g, goff, bta, boff, out, rs, rq);
}

// ---------------- MFMA bf16 GEMM body: C[128x128 tile] = A[M,K](bf16) @ W[K,N] + bias ----------------
// BK=32, 4 waves (2x2), wave = 64x64 via 4x4 16x16x32 frags.
// Double-buffered LDS; global loads for step t+1 issued before MFMA on step t (T3-minimum).
// LDS layout: As (row*64 + k*2)^((row&7)<<4) bytes; Bt[col][k] same swizzle; read as b128.
template<bool WBF, bool GELU_ACT, bool RES, bool OBF>
__device__ void mgemm_body(char* lds, int bm, int bn, const u16* __restrict__ A,
    const void* __restrict__ W, size_t woff,
    const void* __restrict__ bias, size_t boff,
    const float* __restrict__ res, void* __restrict__ C,
    int N, int K)
{
    int tid = threadIdx.x;
    int lane = tid & 63, wave = tid >> 6;
    int wr = (wave >> 1) * 64, wc = (wave & 1) * 64;
    int lr = lane & 15, lk = lane >> 4;

    int arow0 = tid >> 2, akb = tid & 3;     // A staging: (row, k-chunk)
    int bcp = tid & 63, bkh = tid >> 6;      // B staging: col-pair 2*bcp, k-oct bkh*8
    int c0 = 2 * bcp;

    char* As0 = lds;          char* Bt0 = lds + 8192;
    char* As1 = lds + 16384;  char* Bt1 = lds + 24576;

    f32x4 acc[4][4] = {};
    uint4 aReg0, aReg1;
    uint4 bReg0, bReg1;

    auto LOADG = [&](int k0) {
        aReg0 = *(const uint4*)(A + (size_t)(bm + arow0) * K + k0 + akb * 8);
        aReg1 = *(const uint4*)(A + (size_t)(bm + arow0 + 64) * K + k0 + akb * 8);
        u32 wlo[4] = {0,0,0,0}, whi[4] = {0,0,0,0};
#pragma unroll
        for (int i = 0; i < 8; ++i) {
            int kk = k0 + bkh * 8 + i;
            u32 lo, hi;
            if (WBF) {
                u32 pr = *(const u32*)((const u16*)W + woff + (size_t)kk * N + bn + c0);
                lo = pr & 0xffffu; hi = pr >> 16;
            } else {
                const float* wp = (const float*)W + woff + (size_t)kk * N + bn + c0;
                lo = f2b(wp[0]); hi = f2b(wp[1]);
            }
            u32 sh = (u32)(i & 1) * 16;
            wlo[i >> 1] |= lo << sh;
            whi[i >> 1] |= hi << sh;
        }
        bReg0.x = wlo[0]; bReg0.y = wlo[1]; bReg0.z = wlo[2]; bReg0.w = wlo[3];
        bReg1.x = whi[0]; bReg1.y = whi[1]; bReg1.z = whi[2]; bReg1.w = whi[3];
    };
    auto STORE = [&](char* AsB, char* BtB) {
        *(uint4*)(AsB + ((arow0 * 64 + akb * 16) ^ ((arow0 & 7) << 4))) = aReg0;
        *(uint4*)(AsB + (((arow0 + 64) * 64 + akb * 16) ^ (((arow0 + 64) & 7) << 4))) = aReg1;
        *(uint4*)(BtB + ((c0 * 64 + bkh * 16) ^ ((c0 & 7) << 4))) = bReg0;
        *(uint4*)(BtB + (((c0 + 1) * 64 + bkh * 16) ^ (((c0 + 1) & 7) << 4))) = bReg1;
    };
    auto COMPUTE = [&](char* AsB, char* BtB) {
        bf16x8 af[4], bfg[4];
#pragma unroll
        for (int m = 0; m < 4; ++m) {
            int row = wr + m * 16 + lr;
            af[m] = *(const bf16x8*)(AsB + ((row * 64 + lk * 16) ^ ((row & 7) << 4)));
        }
#pragma unroll
        for (int n = 0; n < 4; ++n) {
            int col = wc + n * 16 + lr;
            bfg[n] = *(const bf16x8*)(BtB + ((col * 64 + lk * 16) ^ ((col & 7) << 4)));
        }
#pragma unroll
        for (int m = 0; m < 4; ++m)
#pragma unroll
            for (int n = 0; n < 4; ++n)
                acc[m][n] = __builtin_amdgcn_mfma_f32_16x16x32_bf16(af[m], bfg[n], acc[m][n], 0, 0, 0);
    };

    int nt = K >> 5;
    LOADG(0);
    STORE(As0, Bt0);
    __syncthreads();
    for (int t = 0; t < nt; ++t) {
        bool more = (t + 1 < nt);
        if (more) LOADG((t + 1) << 5);          // issue next-tile global loads early
        if (t & 1) COMPUTE(As1, Bt1);
        else       COMPUTE(As0, Bt0);
        if (more) { if (t & 1) STORE(As0, Bt0); else STORE(As1, Bt1); }
        __syncthreads();                         // one barrier per K-step
    }

    // ---- epilogue: D-layout row=(lane>>4)*4+r, col=lane&15 ----
#pragma unroll
    for (int m = 0; m < 4; ++m) {
        int row0 = bm + wr + m * 16 + lk * 4;
#pragma unroll
        for (int n = 0; n < 4; ++n) {
            int col = bn + wc + n * 16 + lr;
            float bv = WBF ? b2f(((const u16*)bias)[boff + col]) : ((const float*)bias)[boff + col];
#pragma unroll
            for (int r = 0; r < 4; ++r) {
                float vv = acc[m][n][r] + bv;
                if (GELU_ACT) vv = 0.5f * vv * (1.0f + erff(vv * 0.7071067811865475f));
                size_t idx = (size_t)(row0 + r) * N + col;
                if (RES) vv += res[idx];
                if (OBF) ((u16*)C)[idx] = f2b(vv);
                else     ((float*)C)[idx] = vv;
            }
        }
    }
}

// 1-D grid; m-fastest tile order after XCD swizzle (weight N-tile shared by
// consecutive blocks -> L2 reuse; A fits L2 anyway).
template<bool GELU_ACT, bool RES, int OMODE>   // OMODE: 0=f32 out, 1=bf16 out, 2=follow flag
__global__ __launch_bounds__(256) void mgemm_kernel(
    const int* __restrict__ flag, const u16* __restrict__ A,
    const void* __restrict__ W, size_t woff,
    const void* __restrict__ bias, size_t boff,
    const float* __restrict__ res, void* __restrict__ C,
    int N, int K, int gm)
{
    __shared__ __align__(16) char lds[32768];
    int swz = xcd_swizzle(blockIdx.x, gridDim.x);
    int bm = (swz % gm) * 128, bn = (swz / gm) * 128;
    if (*flag) {
        if (OMODE == 0) mgemm_body<true, GELU_ACT, RES, false>(lds, bm, bn, A, W, woff, bias, boff, res, C, N, K);
        else            mgemm_body<true, GELU_ACT, RES, true >(lds, bm, bn, A, W, woff, bias, boff, res, C, N, K);
    } else {
        if (OMODE == 1) mgemm_body<false, GELU_ACT, RES, true >(lds, bm, bn, A, W, woff, bias, boff, res, C, N, K);
        else            mgemm_body<false, GELU_ACT, RES, false>(lds, bm, bn, A, W, woff, bias, boff, res, C, N, K);
    }
}

// Fused QKV: N = 3*768 logical; tile_n/6 selects {Wq,Wk,Wv}; one launch, 288 blocks.
__global__ __launch_bounds__(256) void qkv_kernel(
    const int* __restrict__ flag, const u16* __restrict__ A,
    const void* __restrict__ Wq, const void* __restrict__ Wk, const void* __restrict__ Wv,
    size_t woff,
    const void* __restrict__ bq, const void* __restrict__ bk_, const void* __restrict__ bv_,
    size_t boff,
    u16* __restrict__ qb, u16* __restrict__ kb, u16* __restrict__ vb, int K)
{
    __shared__ __align__(16) char lds[32768];
    int swz = xcd_swizzle(blockIdx.x, gridDim.x);
    int gm = MR >> 7;                 // 16
    int bm = (swz % gm) * 128;
    int tn = swz / gm;                // 0..17
    int which = tn / 6;
    int bn = (tn % 6) * 128;
    const void* W = which == 0 ? Wq : which == 1 ? Wk : Wv;
    const void* bias = which == 0 ? bq : which == 1 ? bk_ : bv_;
    u16* C = which == 0 ? qb : which == 1 ? kb : vb;
    if (*flag) mgemm_body<true,  false, false, true>(lds, bm, bn, A, W, woff, bias, boff, nullptr, C, DD, K);
    else       mgemm_body<false, false, false, true>(lds, bm, bn, A, W, woff, bias, boff, nullptr, C, DD, K);
}

// ---------------- flash attention: block = (b, h, 64-q-tile), 4 waves, bf16 MFMA ----------------
__global__ __launch_bounds__(256) void fattn_kernel(
    const u16* __restrict__ q, const u16* __restrict__ k,
    const u16* __restrict__ v, u16* __restrict__ y)
{
    int q0 = blockIdx.x * 64, h = blockIdx.y, b = blockIdx.z;
    int tid = threadIdx.x, lane = tid & 63, wave = tid >> 6;
    int lr = lane & 15, lk = lane >> 4;

    __shared__ __align__(16) u16 Kt[4096];      // (j*128 + d*2)^((j&7)<<4)
    __shared__ __align__(16) u16 Vt[4096];      // (d*128 + j*2)^((d&7)<<4)
    __shared__ __align__(16) u16 Pt[4][1024];   // per wave: (qr*128 + j*2)^((qr&7)<<4)

    const size_t base = (size_t)b * SS * DD + (size_t)h * DHH;

    int qrow = q0 + wave * 16 + lr;
    bf16x8 qf[2];
#pragma unroll
    for (int ks = 0; ks < 2; ++ks)
        qf[ks] = *(const bf16x8*)(q + base + (size_t)qrow * DD + ks * 32 + lk * 8);

    f32x4 o[4] = {};
    float m_run[4] = {-1e30f, -1e30f, -1e30f, -1e30f};
    float l_run[4] = {0.f, 0.f, 0.f, 0.f};

    int kjr = tid >> 2, kdq = tid & 3;    // K staging: row, d-chunk
    int vdc = tid & 63, vjh = tid >> 6;   // V staging: d-col, j-quarter

    int ntiles = (q0 >> 6) + 1;
    for (int t = 0; t < ntiles; ++t) {
        int j0 = t * 64;
        { // stage K
            const uint4* src = (const uint4*)(k + base + (size_t)(j0 + kjr) * DD + kdq * 16);
            uint4 a0 = src[0], a1 = src[1];
            int ob = kjr * 128 + kdq * 32, sw = (kjr & 7) << 4;
            *(uint4*)((char*)Kt + (ob ^ sw)) = a0;
            *(uint4*)((char*)Kt + ((ob + 16) ^ sw)) = a1;
        }
        { // stage V^T
            const u16* src = v + base + (size_t)(j0 + vjh * 16) * DD + vdc;
            u32 wv[8];
#pragma unroll
            for (int i = 0; i < 8; ++i) {
                u32 a = src[(size_t)(2 * i) * DD];
                u32 bb = src[(size_t)(2 * i + 1) * DD];
                wv[i] = a | (bb << 16);
            }
            uint4 v0; v0.x = wv[0]; v0.y = wv[1]; v0.z = wv[2]; v0.w = wv[3];
            uint4 v1; v1.x = wv[4]; v1.y = wv[5]; v1.z = wv[6]; v1.w = wv[7];
            int ob = vdc * 128 + vjh * 32, sw = (vdc & 7) << 4;
            *(uint4*)((char*)Vt + (ob ^ sw)) = v0;
            *(uint4*)((char*)Vt + ((ob + 16) ^ sw)) = v1;
        }
        __syncthreads();

        // S = Q K^T (wave: 16 q x 64 j)
        f32x4 sv[4] = {};
#pragma unroll
        for (int ks = 0; ks < 2; ++ks) {
#pragma unroll
            for (int n = 0; n < 4; ++n) {
                int col = n * 16 + lr;
                bf16x8 kf = *(const bf16x8*)((char*)Kt + ((col * 128 + ks * 64 + lk * 16) ^ ((col & 7) << 4)));
                sv[n] = __builtin_amdgcn_mfma_f32_16x16x32_bf16(qf[ks], kf, sv[n], 0, 0, 0);
            }
        }

        // scale + causal mask + online softmax (row = lk*4 + r)
#pragma unroll
        for (int r = 0; r < 4; ++r) {
            int qg = q0 + wave * 16 + lk * 4 + r;
            float s0 = sv[0][r] * 0.125f, s1 = sv[1][r] * 0.125f;
            float s2 = sv[2][r] * 0.125f, s3 = sv[3][r] * 0.125f;
            if (j0 +  0 + lr > qg) s0 = -1e30f;
            if (j0 + 16 + lr > qg) s1 = -1e30f;
            if (j0 + 32 + lr > qg) s2 = -1e30f;
            if (j0 + 48 + lr > qg) s3 = -1e30f;
            float mx = fmaxf(fmaxf(s0, s1), fmaxf(s2, s3));
            mx = fmaxf(mx, __shfl_xor(mx, 1));
            mx = fmaxf(mx, __shfl_xor(mx, 2));
            mx = fmaxf(mx, __shfl_xor(mx, 4));
            mx = fmaxf(mx, __shfl_xor(mx, 8));
            float mnew = fmaxf(m_run[r], mx);
            float alpha = __expf(m_run[r] - mnew);
            m_run[r] = mnew;
            float p0 = __expf(s0 - mnew), p1 = __expf(s1 - mnew);
            float p2 = __expf(s2 - mnew), p3 = __expf(s3 - mnew);
            float rsum = p0 + p1 + p2 + p3;
            rsum += __shfl_xor(rsum, 1); rsum += __shfl_xor(rsum, 2);
            rsum += __shfl_xor(rsum, 4); rsum += __shfl_xor(rsum, 8);
            l_run[r] = l_run[r] * alpha + rsum;
            o[0][r] *= alpha; o[1][r] *= alpha; o[2][r] *= alpha; o[3][r] *= alpha;
            sv[0][r] = p0; sv[1][r] = p1; sv[2][r] = p2; sv[3][r] = p3;
        }

        // P (bf16) -> per-wave LDS transpose (D-layout -> A-layout)
        u16* pw = Pt[wave];
#pragma unroll
        for (int n = 0; n < 4; ++n)
#pragma unroll
            for (int r = 0; r < 4; ++r) {
                int prow = lk * 4 + r, pcol = n * 16 + lr;
                *(u16*)((char*)pw + ((prow * 128 + pcol * 2) ^ ((prow & 7) << 4))) = f2b(sv[n][r]);
            }

        // O += P V
#pragma unroll
        for (int ks = 0; ks < 2; ++ks) {
            bf16x8 pa = *(const bf16x8*)((char*)pw + ((lr * 128 + ks * 64 + lk * 16) ^ ((lr & 7) << 4)));
#pragma unroll
            for (int dn = 0; dn < 4; ++dn) {
                int col = dn * 16 + lr;
                bf16x8 vf = *(const bf16x8*)((char*)Vt + ((col * 128 + ks * 64 + lk * 16) ^ ((col & 7) << 4)));
                o[dn] = __builtin_amdgcn_mfma_f32_16x16x32_bf16(pa, vf, o[dn], 0, 0, 0);
            }
        }
        __syncthreads();
    }

    // write O / l  (bf16)
#pragma unroll
    for (int dn = 0; dn < 4; ++dn)
#pragma unroll
        for (int r = 0; r < 4; ++r) {
            int qg = q0 + wave * 16 + lk * 4 + r;
            y[base + (size_t)qg * DD + dn * 16 + lr] = f2b(o[dn][r] / l_run[r]);
        }
}

extern "C" void kernel_launch(void* const* d_in, const int* in_sizes, int n_in,
                              void* d_out, int out_size, void* d_ws, size_t ws_size,
                              hipStream_t stream)
{
    const int* tokens = (const int*)d_in[0];
    const void* tok_emb = d_in[1];
    const void *Wq = d_in[2], *bq = d_in[3], *Wk = d_in[4], *bk = d_in[5];
    const void *Wv = d_in[6], *bv = d_in[7], *Wo = d_in[8], *bo = d_in[9];
    const void *ln1_g = d_in[10], *ln1_b = d_in[11], *ln2_g = d_in[12], *ln2_b = d_in[13];
    const void *W1 = d_in[14], *b1 = d_in[15], *W2 = d_in[16], *b2 = d_in[17];
    const void *lnf_g = d_in[18], *lnf_b = d_in[19], *fc_W = d_in[20], *fc_b = d_in[21];

    // d_ws layout: [flag 256B][x MR*DD f32][hbuf MR*DD bf16][big: q/k/v bf16 | ffb bf16]
    int* flag = (int*)d_ws;
    float* x  = (float*)((char*)d_ws + 256);
    u16* hbuf = (u16*)(x + (size_t)MR * DD);
    u16* big  = hbuf + (size_t)MR * DD;
    u16* qb = big;
    u16* kb = big + (size_t)MR * DD;
    u16* vb = big + 2 * (size_t)MR * DD;
    u16* ffb = big;   // [2048,3072] bf16, aliases q/k/v after attention

    dim3 blk(256);
    const int GM = MR / 128;                 // 16
    int nD = GM * (DD / 128);                // 96
    int nQKV = GM * (3 * DD / 128);          // 288
    int nF = GM * (FF / 128);                // 384
    int nV = GM * (VV / 128);                // 4000

    detect_kernel<<<1, 1, 0, stream>>>((const unsigned*)ln1_g, flag);
    embed_kernel<<<MR, blk, 0, stream>>>(flag, tokens, tok_emb, x);

    for (int l = 0; l < LL; ++l) {
        size_t oW  = (size_t)l * DD * DD, oB  = (size_t)l * DD;
        size_t oW1 = (size_t)l * DD * FF, oB1 = (size_t)l * FF;
        size_t oW2 = (size_t)l * FF * DD;

        ln_kernel<<<MR, blk, 0, stream>>>(flag, x, ln1_g, oB, ln1_b, oB, hbuf);
        qkv_kernel<<<nQKV, blk, 0, stream>>>(
            flag, hbuf, Wq, Wk, Wv, oW, bq, bk, bv, oB, qb, kb, vb, DD);
        fattn_kernel<<<dim3(SS / 64, HH, BB), blk, 0, stream>>>(qb, kb, vb, hbuf);
        mgemm_kernel<false, true, 0><<<nD, blk, 0, stream>>>(
            flag, hbuf, Wo, oW, bo, oB, x, x, DD, DD, GM);
        ln_kernel<<<MR, blk, 0, stream>>>(flag, x, ln2_g, oB, ln2_b, oB, hbuf);
        mgemm_kernel<true, false, 1><<<nF, blk, 0, stream>>>(
            flag, hbuf, W1, oW1, b1, oB1, nullptr, ffb, FF, DD, GM);
        mgemm_kernel<false, true, 0><<<nD, blk, 0, stream>>>(
            flag, ffb, W2, oW2, b2, oB, x, x, DD, FF, GM);
    }

    ln_kernel<<<MR, blk, 0, stream>>>(flag, x, lnf_g, 0, lnf_b, 0, hbuf);
    mgemm_kernel<false, false, 2><<<nV, blk, 0, stream>>>(
        flag, hbuf, fc_W, 0, fc_b, 0, nullptr, d_out, VV, DD, GM);
}

// Round 3
// 1407.201 us; speedup vs baseline: 1.6458x; 1.6458x over previous
//
#include <hip/hip_runtime.h>
#include <hip/hip_bf16.h>
#include <math.h>

#define BB 2
#define SS 1024
#define DD 768
#define HH 12
#define DHH 64
#define LL 4
#define VV 32000
#define FF 3072
#define MR (BB*SS)   // 2048 rows

typedef unsigned short u16;
typedef unsigned int u32;
typedef __hip_bfloat16 bf16;

using f32x4  = __attribute__((ext_vector_type(4))) float;
using bf16x8 = __attribute__((ext_vector_type(8))) short;   // 8 bf16 in 4 VGPRs

__device__ inline u16 f2b(float f) {
    union { bf16 h; u16 u; } c; c.h = __float2bfloat16(f); return c.u;
}
__device__ inline float b2f(u16 u) {
    union { u16 u; bf16 h; } c; c.u = u; return __bfloat162float(c.h);
}

template<bool BF>
__device__ inline float ldg_t(const void* p, size_t i) {
    if (BF) return b2f(((const u16*)p)[i]);
    else    return ((const float*)p)[i];
}

// bijective XCD-aware block swizzle (m204)
__device__ inline int xcd_swizzle(int orig, int nwg) {
    int q = nwg >> 3, r = nwg & 7;
    int xcd = orig & 7, pos = orig >> 3;
    return (xcd < r ? xcd * (q + 1) : r * (q + 1) + (xcd - r) * q) + pos;
}

// ---------------- dtype detect: ln1_g is all ones ----------------
__global__ void detect_kernel(const unsigned* __restrict__ ln1g, int* __restrict__ flag) {
    *flag = (ln1g[0] == 0x3F803F80u) ? 1 : 0;   // bf16 ones pair vs f32 one
}

// ---------------- embedding + positional encoding (x stays f32) ----------------
template<bool BF>
__device__ void embed_body(const int* tokens, const void* tok_emb, float* x) {
    int row = blockIdx.x;
    int s = row & (SS - 1);
    int tok = tokens[row];
    const float scale = 27.712812921102035f;   // sqrt(768)
    for (int d = threadIdx.x; d < DD; d += 256) {
        float val = ldg_t<BF>(tok_emb, (size_t)tok * DD + d) * scale;
        int i2 = d & ~1;
        float freq = expf(-9.210340371976184f * (float)i2 / (float)DD);
        float arg = (float)s * freq;
        val += (d & 1) ? cosf(arg) : sinf(arg);
        x[(size_t)row * DD + d] = val;
    }
}
__global__ __launch_bounds__(256) void embed_kernel(
    const int* __restrict__ flag, const int* __restrict__ tokens,
    const void* __restrict__ tok_emb, float* __restrict__ x)
{
    if (*flag) embed_body<true>(tokens, tok_emb, x);
    else       embed_body<false>(tokens, tok_emb, x);
}

// ---------------- layernorm (row of 768), f32 in -> bf16 out ----------------
template<bool BF>
__device__ void ln_body(const float* x, const void* g, size_t goff,
                        const void* bta, size_t boff, u16* out,
                        float* rs, float* rq) {
    int row = blockIdx.x;
    const float* xr = x + (size_t)row * DD;
    int t = threadIdx.x;
    float v0 = xr[t], v1 = xr[t + 256], v2 = xr[t + 512];
    float s = v0 + v1 + v2;
    float sq = v0 * v0 + v1 * v1 + v2 * v2;
    for (int off = 32; off; off >>= 1) { s += __shfl_xor(s, off); sq += __shfl_xor(sq, off); }
    int wave = t >> 6, lane = t & 63;
    if (lane == 0) { rs[wave] = s; rq[wave] = sq; }
    __syncthreads();
    s = rs[0] + rs[1] + rs[2] + rs[3];
    sq = rq[0] + rq[1] + rq[2] + rq[3];
    float mu = s * (1.0f / DD);
    float var = sq * (1.0f / DD) - mu * mu;
    float rstd = rsqrtf(var + 1e-5f);
    u16* orow = out + (size_t)row * DD;
    orow[t]       = f2b((v0 - mu) * rstd * ldg_t<BF>(g, goff + t)       + ldg_t<BF>(bta, boff + t));
    orow[t + 256] = f2b((v1 - mu) * rstd * ldg_t<BF>(g, goff + t + 256) + ldg_t<BF>(bta, boff + t + 256));
    orow[t + 512] = f2b((v2 - mu) * rstd * ldg_t<BF>(g, goff + t + 512) + ldg_t<BF>(bta, boff + t + 512));
}
__global__ __launch_bounds__(256) void ln_kernel(
    const int* __restrict__ flag, const float* __restrict__ x,
    const void* __restrict__ g, size_t goff,
    const void* __restrict__ bta, size_t boff, u16* __restrict__ out)
{
    __shared__ float rs[4], rq[4];
    if (*flag) ln_body<true>(x, g, goff, bta, boff, out, rs, rq);
    else       ln_body<false>(x, g, goff, bta, boff, out, rs, rq);
}

// ---------------- weight transpose+convert: f32/bf16 [K][N] -> bf16 [N][K] arena ----------------
struct TransJobs {
    const void* src[7];
    unsigned long long dstoff[7];  // element offset in arena
    int Kd[7], Nd[7];
    int cum[8];                    // cumulative 32x32-tile counts (layers folded)
};
__global__ __launch_bounds__(256) void trans_kernel(
    const int* __restrict__ flag, TransJobs J, u16* __restrict__ arena)
{
    __shared__ float tile[32][33];
    int bid = blockIdx.x;
    int t = 0;
    while (bid >= J.cum[t + 1]) ++t;
    int local = bid - J.cum[t];
    int Kt = J.Kd[t], Nt = J.Nd[t];
    int ntn = Nt >> 5;
    int tpl = (Kt >> 5) * ntn;
    int layer = local / tpl, rem = local - layer * tpl;
    int tk = rem / ntn, tn = rem - tk * ntn;
    int n0 = tn << 5, k0 = tk << 5;
    const char* srcb = (const char*)J.src[t];
    int BF = *flag;
    size_t sbase = (size_t)layer * Kt * Nt;
    int tx = threadIdx.x & 31, ty = threadIdx.x >> 5;
#pragma unroll
    for (int i = 0; i < 4; ++i) {
        int kk = k0 + ty + i * 8;
        size_t si = sbase + (size_t)kk * Nt + n0 + tx;
        tile[ty + i * 8][tx] = BF ? b2f(((const u16*)srcb)[si]) : ((const float*)srcb)[si];
    }
    __syncthreads();
    u16* dst = arena + J.dstoff[t] + sbase;
#pragma unroll
    for (int i = 0; i < 4; ++i) {
        int nn = n0 + ty + i * 8;
        dst[(size_t)nn * Kt + k0 + tx] = f2b(tile[tx][ty + i * 8]);
    }
}

// ---------------- arena-path MFMA GEMM: C = A[M,K](bf16) @ WT[N,K](bf16)^T + bias ----------------
// 128 x (NF*32) block tile, BK=32, 4 waves (2x2), double-buffered LDS.
// LOADG = pure loads (vmcnt wait lands after COMPUTE), STORE after COMPUTE, one barrier/step.
template<int NF, bool BBF, bool GELU_ACT, bool RES, bool OBF>
__device__ void agemm_body(char* lds, int bm, int bn,
    const u16* __restrict__ A, const u16* __restrict__ WT,
    const void* __restrict__ bias, size_t boff,
    const float* __restrict__ res, void* __restrict__ C,
    int N, int K)
{
    constexpr int BNB = NF * 32 * 64;   // Bt buffer bytes
    char* As0 = lds;
    char* As1 = lds + 8192;
    char* Bt0 = lds + 16384;
    char* Bt1 = lds + 16384 + BNB;

    int tid = threadIdx.x;
    int lane = tid & 63, wave = tid >> 6;
    int wr = (wave >> 1) * 64, wc = (wave & 1) * (NF * 16);
    int lr = lane & 15, lk = lane >> 4;
    int arow0 = tid >> 2, akb = tid & 3;

    f32x4 acc[4][NF] = {};
    uint4 aR0, aR1, bR0, bR1;

    auto LOADG = [&](int k0) {
        aR0 = *(const uint4*)(A + (size_t)(bm + arow0) * K + k0 + akb * 8);
        aR1 = *(const uint4*)(A + (size_t)(bm + arow0 + 64) * K + k0 + akb * 8);
        bR0 = *(const uint4*)(WT + (size_t)(bn + arow0) * K + k0 + akb * 8);
        if (NF == 4)
            bR1 = *(const uint4*)(WT + (size_t)(bn + arow0 + 64) * K + k0 + akb * 8);
    };
    auto STORE = [&](char* AsB, char* BtB) {
        int sw = (arow0 & 7) << 4;
        *(uint4*)(AsB + ((arow0 * 64 + akb * 16) ^ sw)) = aR0;
        *(uint4*)(AsB + (((arow0 + 64) * 64 + akb * 16) ^ sw)) = aR1;
        *(uint4*)(BtB + ((arow0 * 64 + akb * 16) ^ sw)) = bR0;
        if (NF == 4)
            *(uint4*)(BtB + (((arow0 + 64) * 64 + akb * 16) ^ sw)) = bR1;
    };
    auto COMPUTE = [&](char* AsB, char* BtB) {
        bf16x8 af[4], bfg[NF];
#pragma unroll
        for (int m = 0; m < 4; ++m) {
            int row = wr + m * 16 + lr;
            af[m] = *(const bf16x8*)(AsB + ((row * 64 + lk * 16) ^ ((row & 7) << 4)));
        }
#pragma unroll
        for (int n = 0; n < NF; ++n) {
            int col = wc + n * 16 + lr;
            bfg[n] = *(const bf16x8*)(BtB + ((col * 64 + lk * 16) ^ ((col & 7) << 4)));
        }
#pragma unroll
        for (int m = 0; m < 4; ++m)
#pragma unroll
            for (int n = 0; n < NF; ++n)
                acc[m][n] = __builtin_amdgcn_mfma_f32_16x16x32_bf16(af[m], bfg[n], acc[m][n], 0, 0, 0);
    };

    int nt = K >> 5;
    LOADG(0);
    STORE(As0, Bt0);
    __syncthreads();
    for (int t = 0; t < nt; ++t) {
        bool more = (t + 1 < nt);
        if (more) LOADG((t + 1) << 5);                       // issue only
        if (t & 1) COMPUTE(As1, Bt1); else COMPUTE(As0, Bt0); // MFMA hides load latency
        if (more) { if (t & 1) STORE(As0, Bt0); else STORE(As1, Bt1); }
        __syncthreads();
    }

    // epilogue: D-layout row=(lane>>4)*4+r, col=lane&15
#pragma unroll
    for (int m = 0; m < 4; ++m) {
        int row0 = bm + wr + m * 16 + lk * 4;
#pragma unroll
        for (int n = 0; n < NF; ++n) {
            int col = bn + wc + n * 16 + lr;
            float bv = BBF ? b2f(((const u16*)bias)[boff + col]) : ((const float*)bias)[boff + col];
#pragma unroll
            for (int r = 0; r < 4; ++r) {
                float vv = acc[m][n][r] + bv;
                if (GELU_ACT) vv = 0.5f * vv * (1.0f + erff(vv * 0.7071067811865475f));
                size_t idx = (size_t)(row0 + r) * N + col;
                if (RES) vv += res[idx];
                if (OBF) ((u16*)C)[idx] = f2b(vv);
                else     ((float*)C)[idx] = vv;
            }
        }
    }
}

template<int NF, bool GELU_ACT, bool RES, int OMODE>   // OMODE: 0=f32 out, 1=bf16 out, 2=follow flag
__global__ __launch_bounds__(256) void agemm_kernel(
    const int* __restrict__ flag, const u16* __restrict__ A, const u16* __restrict__ WT,
    const void* __restrict__ bias, size_t boff,
    const float* __restrict__ res, void* __restrict__ C,
    int N, int K, int gm)
{
    __shared__ __align__(16) char lds[16384 + 2 * NF * 32 * 64];
    int swz = xcd_swizzle(blockIdx.x, gridDim.x);
    int bm = (swz % gm) * 128, bn = (swz / gm) * (NF * 32);
    if (*flag) agemm_body<NF, true,  GELU_ACT, RES, (OMODE != 0)>(lds, bm, bn, A, WT, bias, boff, res, C, N, K);
    else       agemm_body<NF, false, GELU_ACT, RES, (OMODE == 1)>(lds, bm, bn, A, WT, bias, boff, res, C, N, K);
}

// Fused QKV from arena (288 blocks)
__global__ __launch_bounds__(256) void aqkv_kernel(
    const int* __restrict__ flag, const u16* __restrict__ A,
    const u16* __restrict__ WqT, const u16* __restrict__ WkT, const u16* __restrict__ WvT,
    const void* __restrict__ bq, const void* __restrict__ bk_, const void* __restrict__ bv_,
    size_t boff, u16* __restrict__ qb, u16* __restrict__ kb, u16* __restrict__ vb)
{
    __shared__ __align__(16) char lds[32768];
    int swz = xcd_swizzle(blockIdx.x, gridDim.x);
    int gm = MR >> 7;
    int bm = (swz % gm) * 128;
    int tn = swz / gm;
    int which = tn / 6;
    int bn = (tn % 6) * 128;
    const u16* WT = which == 0 ? WqT : which == 1 ? WkT : WvT;
    const void* bias = which == 0 ? bq : which == 1 ? bk_ : bv_;
    u16* C = which == 0 ? qb : which == 1 ? kb : vb;
    if (*flag) agemm_body<4, true,  false, false, true>(lds, bm, bn, A, WT, bias, boff, nullptr, C, DD, DD);
    else       agemm_body<4, false, false, false, true>(lds, bm, bn, A, WT, bias, boff, nullptr, C, DD, DD);
}

// ---------------- fallback GEMM (no arena): round-2 path, used only if ws too small ----------------
template<bool WBF, bool GELU_ACT, bool RES, bool OBF>
__device__ void mgemm_body(char* lds, int bm, int bn, const u16* __restrict__ A,
    const void* __restrict__ W, size_t woff,
    const void* __restrict__ bias, size_t boff,
    const float* __restrict__ res, void* __restrict__ C,
    int N, int K)
{
    int tid = threadIdx.x;
    int lane = tid & 63, wave = tid >> 6;
    int wr = (wave >> 1) * 64, wc = (wave & 1) * 64;
    int lr = lane & 15, lk = lane >> 4;
    int arow0 = tid >> 2, akb = tid & 3;
    int bcp = tid & 63, bkh = tid >> 6;
    int c0 = 2 * bcp;
    char* As0 = lds;          char* Bt0 = lds + 8192;
    f32x4 acc[4][4] = {};
    for (int k0 = 0; k0 < K; k0 += 32) {
#pragma unroll
        for (int p = 0; p < 2; ++p) {
            int row = arow0 + p * 64;
            uint4 val = *(const uint4*)(A + (size_t)(bm + row) * K + k0 + akb * 8);
            *(uint4*)(As0 + ((row * 64 + akb * 16) ^ ((row & 7) << 4))) = val;
        }
        {
            u32 wlo[4] = {0,0,0,0}, whi[4] = {0,0,0,0};
#pragma unroll
            for (int i = 0; i < 8; ++i) {
                int kk = k0 + bkh * 8 + i;
                u32 lo, hi;
                if (WBF) {
                    u32 pr = *(const u32*)((const u16*)W + woff + (size_t)kk * N + bn + c0);
                    lo = pr & 0xffffu; hi = pr >> 16;
                } else {
                    const float* wp = (const float*)W + woff + (size_t)kk * N + bn + c0;
                    lo = f2b(wp[0]); hi = f2b(wp[1]);
                }
                u32 sh = (u32)(i & 1) * 16;
                wlo[i >> 1] |= lo << sh;
                whi[i >> 1] |= hi << sh;
            }
            uint4 v0; v0.x = wlo[0]; v0.y = wlo[1]; v0.z = wlo[2]; v0.w = wlo[3];
            uint4 v1; v1.x = whi[0]; v1.y = whi[1]; v1.z = whi[2]; v1.w = whi[3];
            *(uint4*)(Bt0 + ((c0 * 64 + bkh * 16) ^ ((c0 & 7) << 4))) = v0;
            *(uint4*)(Bt0 + (((c0 + 1) * 64 + bkh * 16) ^ (((c0 + 1) & 7) << 4))) = v1;
        }
        __syncthreads();
        bf16x8 af[4], bfg[4];
#pragma unroll
        for (int m = 0; m < 4; ++m) {
            int row = wr + m * 16 + lr;
            af[m] = *(const bf16x8*)(As0 + ((row * 64 + lk * 16) ^ ((row & 7) << 4)));
        }
#pragma unroll
        for (int n = 0; n < 4; ++n) {
            int col = wc + n * 16 + lr;
            bfg[n] = *(const bf16x8*)(Bt0 + ((col * 64 + lk * 16) ^ ((col & 7) << 4)));
        }
#pragma unroll
        for (int m = 0; m < 4; ++m)
#pragma unroll
            for (int n = 0; n < 4; ++n)
                acc[m][n] = __builtin_amdgcn_mfma_f32_16x16x32_bf16(af[m], bfg[n], acc[m][n], 0, 0, 0);
        __syncthreads();
    }
#pragma unroll
    for (int m = 0; m < 4; ++m) {
        int row0 = bm + wr + m * 16 + lk * 4;
#pragma unroll
        for (int n = 0; n < 4; ++n) {
            int col = bn + wc + n * 16 + lr;
            float bv = WBF ? b2f(((const u16*)bias)[boff + col]) : ((const float*)bias)[boff + col];
#pragma unroll
            for (int r = 0; r < 4; ++r) {
                float vv = acc[m][n][r] + bv;
                if (GELU_ACT) vv = 0.5f * vv * (1.0f + erff(vv * 0.7071067811865475f));
                size_t idx = (size_t)(row0 + r) * N + col;
                if (RES) vv += res[idx];
                if (OBF) ((u16*)C)[idx] = f2b(vv);
                else     ((float*)C)[idx] = vv;
            }
        }
    }
}
template<bool GELU_ACT, bool RES, int OMODE>
__global__ __launch_bounds__(256) void mgemm_kernel(
    const int* __restrict__ flag, const u16* __restrict__ A,
    const void* __restrict__ W, size_t woff,
    const void* __restrict__ bias, size_t boff,
    const float* __restrict__ res, void* __restrict__ C,
    int N, int K, int gm)
{
    __shared__ __align__(16) char lds[16384];
    int swz = xcd_swizzle(blockIdx.x, gridDim.x);
    int bm = (swz % gm) * 128, bn = (swz / gm) * 128;
    if (*flag) {
        if (OMODE == 0) mgemm_body<true, GELU_ACT, RES, false>(lds, bm, bn, A, W, woff, bias, boff, res, C, N, K);
        else            mgemm_body<true, GELU_ACT, RES, true >(lds, bm, bn, A, W, woff, bias, boff, res, C, N, K);
    } else {
        if (OMODE == 1) mgemm_body<false, GELU_ACT, RES, true >(lds, bm, bn, A, W, woff, bias, boff, res, C, N, K);
        else            mgemm_body<false, GELU_ACT, RES, false>(lds, bm, bn, A, W, woff, bias, boff, res, C, N, K);
    }
}
__global__ __launch_bounds__(256) void qkv_kernel(
    const int* __restrict__ flag, const u16* __restrict__ A,
    const void* __restrict__ Wq, const void* __restrict__ Wk, const void* __restrict__ Wv,
    size_t woff,
    const void* __restrict__ bq, const void* __restrict__ bk_, const void* __restrict__ bv_,
    size_t boff,
    u16* __restrict__ qb, u16* __restrict__ kb, u16* __restrict__ vb, int K)
{
    __shared__ __align__(16) char lds[16384];
    int swz = xcd_swizzle(blockIdx.x, gridDim.x);
    int gm = MR >> 7;
    int bm = (swz % gm) * 128;
    int tn = swz / gm;
    int which = tn / 6;
    int bn = (tn % 6) * 128;
    const void* W = which == 0 ? Wq : which == 1 ? Wk : Wv;
    const void* bias = which == 0 ? bq : which == 1 ? bk_ : bv_;
    u16* C = which == 0 ? qb : which == 1 ? kb : vb;
    if (*flag) mgemm_body<true,  false, false, true>(lds, bm, bn, A, W, woff, bias, boff, nullptr, C, DD, K);
    else       mgemm_body<false, false, false, true>(lds, bm, bn, A, W, woff, bias, boff, nullptr, C, DD, K);
}

// ---------------- flash attention: block = (b, h, 64-q-tile), 4 waves, bf16 MFMA ----------------
__global__ __launch_bounds__(256) void fattn_kernel(
    const u16* __restrict__ q, const u16* __restrict__ k,
    const u16* __restrict__ v, u16* __restrict__ y)
{
    int q0 = blockIdx.x * 64, h = blockIdx.y, b = blockIdx.z;
    int tid = threadIdx.x, lane = tid & 63, wave = tid >> 6;
    int lr = lane & 15, lk = lane >> 4;

    __shared__ __align__(16) u16 Kt[4096];
    __shared__ __align__(16) u16 Vt[4096];
    __shared__ __align__(16) u16 Pt[4][1024];

    const size_t base = (size_t)b * SS * DD + (size_t)h * DHH;

    int qrow = q0 + wave * 16 + lr;
    bf16x8 qf[2];
#pragma unroll
    for (int ks = 0; ks < 2; ++ks)
        qf[ks] = *(const bf16x8*)(q + base + (size_t)qrow * DD + ks * 32 + lk * 8);

    f32x4 o[4] = {};
    float m_run[4] = {-1e30f, -1e30f, -1e30f, -1e30f};
    float l_run[4] = {0.f, 0.f, 0.f, 0.f};

    int kjr = tid >> 2, kdq = tid & 3;
    int vdc = tid & 63, vjh = tid >> 6;

    int ntiles = (q0 >> 6) + 1;
    for (int t = 0; t < ntiles; ++t) {
        int j0 = t * 64;
        {
            const uint4* src = (const uint4*)(k + base + (size_t)(j0 + kjr) * DD + kdq * 16);
            uint4 a0 = src[0], a1 = src[1];
            int ob = kjr * 128 + kdq * 32, sw = (kjr & 7) << 4;
            *(uint4*)((char*)Kt + (ob ^ sw)) = a0;
            *(uint4*)((char*)Kt + ((ob + 16) ^ sw)) = a1;
        }
        {
            const u16* src = v + base + (size_t)(j0 + vjh * 16) * DD + vdc;
            u32 wv[8];
#pragma unroll
            for (int i = 0; i < 8; ++i) {
                u32 a = src[(size_t)(2 * i) * DD];
                u32 bb = src[(size_t)(2 * i + 1) * DD];
                wv[i] = a | (bb << 16);
            }
            uint4 v0; v0.x = wv[0]; v0.y = wv[1]; v0.z = wv[2]; v0.w = wv[3];
            uint4 v1; v1.x = wv[4]; v1.y = wv[5]; v1.z = wv[6]; v1.w = wv[7];
            int ob = vdc * 128 + vjh * 32, sw = (vdc & 7) << 4;
            *(uint4*)((char*)Vt + (ob ^ sw)) = v0;
            *(uint4*)((char*)Vt + ((ob + 16) ^ sw)) = v1;
        }
        __syncthreads();

        f32x4 sv[4] = {};
#pragma unroll
        for (int ks = 0; ks < 2; ++ks) {
#pragma unroll
            for (int n = 0; n < 4; ++n) {
                int col = n * 16 + lr;
                bf16x8 kf = *(const bf16x8*)((char*)Kt + ((col * 128 + ks * 64 + lk * 16) ^ ((col & 7) << 4)));
                sv[n] = __builtin_amdgcn_mfma_f32_16x16x32_bf16(qf[ks], kf, sv[n], 0, 0, 0);
            }
        }

#pragma unroll
        for (int r = 0; r < 4; ++r) {
            int qg = q0 + wave * 16 + lk * 4 + r;
            float s0 = sv[0][r] * 0.125f, s1 = sv[1][r] * 0.125f;
            float s2 = sv[2][r] * 0.125f, s3 = sv[3][r] * 0.125f;
            if (j0 +  0 + lr > qg) s0 = -1e30f;
            if (j0 + 16 + lr > qg) s1 = -1e30f;
            if (j0 + 32 + lr > qg) s2 = -1e30f;
            if (j0 + 48 + lr > qg) s3 = -1e30f;
            float mx = fmaxf(fmaxf(s0, s1), fmaxf(s2, s3));
            mx = fmaxf(mx, __shfl_xor(mx, 1));
            mx = fmaxf(mx, __shfl_xor(mx, 2));
            mx = fmaxf(mx, __shfl_xor(mx, 4));
            mx = fmaxf(mx, __shfl_xor(mx, 8));
            float mnew = fmaxf(m_run[r], mx);
            float alpha = __expf(m_run[r] - mnew);
            m_run[r] = mnew;
            float p0 = __expf(s0 - mnew), p1 = __expf(s1 - mnew);
            float p2 = __expf(s2 - mnew), p3 = __expf(s3 - mnew);
            float rsum = p0 + p1 + p2 + p3;
            rsum += __shfl_xor(rsum, 1); rsum += __shfl_xor(rsum, 2);
            rsum += __shfl_xor(rsum, 4); rsum += __shfl_xor(rsum, 8);
            l_run[r] = l_run[r] * alpha + rsum;
            o[0][r] *= alpha; o[1][r] *= alpha; o[2][r] *= alpha; o[3][r] *= alpha;
            sv[0][r] = p0; sv[1][r] = p1; sv[2][r] = p2; sv[3][r] = p3;
        }

        u16* pw = Pt[wave];
#pragma unroll
        for (int n = 0; n < 4; ++n)
#pragma unroll
            for (int r = 0; r < 4; ++r) {
                int prow = lk * 4 + r, pcol = n * 16 + lr;
                *(u16*)((char*)pw + ((prow * 128 + pcol * 2) ^ ((prow & 7) << 4))) = f2b(sv[n][r]);
            }

#pragma unroll
        for (int ks = 0; ks < 2; ++ks) {
            bf16x8 pa = *(const bf16x8*)((char*)pw + ((lr * 128 + ks * 64 + lk * 16) ^ ((lr & 7) << 4)));
#pragma unroll
            for (int dn = 0; dn < 4; ++dn) {
                int col = dn * 16 + lr;
                bf16x8 vf = *(const bf16x8*)((char*)Vt + ((col * 128 + ks * 64 + lk * 16) ^ ((col & 7) << 4)));
                o[dn] = __builtin_amdgcn_mfma_f32_16x16x32_bf16(pa, vf, o[dn], 0, 0, 0);
            }
        }
        __syncthreads();
    }

#pragma unroll
    for (int dn = 0; dn < 4; ++dn)
#pragma unroll
        for (int r = 0; r < 4; ++r) {
            int qg = q0 + wave * 16 + lk * 4 + r;
            y[base + (size_t)qg * DD + dn * 16 + lr] = f2b(o[dn][r] / l_run[r]);
        }
}

extern "C" void kernel_launch(void* const* d_in, const int* in_sizes, int n_in,
                              void* d_out, int out_size, void* d_ws, size_t ws_size,
                              hipStream_t stream)
{
    const int* tokens = (const int*)d_in[0];
    const void* tok_emb = d_in[1];
    const void *Wq = d_in[2], *bq = d_in[3], *Wk = d_in[4], *bk = d_in[5];
    const void *Wv = d_in[6], *bv = d_in[7], *Wo = d_in[8], *bo = d_in[9];
    const void *ln1_g = d_in[10], *ln1_b = d_in[11], *ln2_g = d_in[12], *ln2_b = d_in[13];
    const void *W1 = d_in[14], *b1 = d_in[15], *W2 = d_in[16], *b2 = d_in[17];
    const void *lnf_g = d_in[18], *lnf_b = d_in[19], *fc_W = d_in[20], *fc_b = d_in[21];

    // ws layout: [flag 256B][x f32][hbuf bf16][big bf16][arena bf16 (weights^T)]
    int* flag = (int*)d_ws;
    float* x  = (float*)((char*)d_ws + 256);
    u16* hbuf = (u16*)(x + (size_t)MR * DD);
    u16* big  = hbuf + (size_t)MR * DD;
    u16* qb = big;
    u16* kb = big + (size_t)MR * DD;
    u16* vb = big + 2 * (size_t)MR * DD;
    u16* ffb = big;                                   // aliases q/k/v after attn
    u16* arena = big + (size_t)MR * FF;               // weights^T arena

    const size_t SZ_D2 = (size_t)DD * DD;             // 589824
    const size_t SZ_DF = (size_t)DD * FF;             // 2359296
    const size_t O_WQ = 0;
    const size_t O_WK = O_WQ + LL * SZ_D2;
    const size_t O_WV = O_WK + LL * SZ_D2;
    const size_t O_WO = O_WV + LL * SZ_D2;
    const size_t O_W1 = O_WO + LL * SZ_D2;
    const size_t O_W2 = O_W1 + LL * SZ_DF;
    const size_t O_FC = O_W2 + LL * SZ_DF;
    const size_t ARENA_ELEMS = O_FC + (size_t)DD * VV;  // 52,887,552
    const size_t need = ((char*)(arena + ARENA_ELEMS)) - (char*)d_ws;
    bool use_arena = ws_size >= need;

    dim3 blk(256);
    const int GM = MR / 128;                 // 16

    detect_kernel<<<1, 1, 0, stream>>>((const unsigned*)ln1_g, flag);
    embed_kernel<<<MR, blk, 0, stream>>>(flag, tokens, tok_emb, x);

    if (use_arena) {
        TransJobs J;
        const void* srcs[7] = { Wq, Wk, Wv, Wo, W1, W2, fc_W };
        unsigned long long offs[7] = { O_WQ, O_WK, O_WV, O_WO, O_W1, O_W2, O_FC };
        int Ks[7] = { DD, DD, DD, DD, DD, FF, DD };
        int Ns[7] = { DD, DD, DD, DD, FF, DD, VV };
        int Ls[7] = { LL, LL, LL, LL, LL, LL, 1 };
        int cum = 0;
        for (int i = 0; i < 7; ++i) {
            J.src[i] = srcs[i]; J.dstoff[i] = offs[i]; J.Kd[i] = Ks[i]; J.Nd[i] = Ns[i];
            J.cum[i] = cum;
            cum += Ls[i] * (Ks[i] >> 5) * (Ns[i] >> 5);
        }
        J.cum[7] = cum;                       // 51648 tiles
        trans_kernel<<<cum, blk, 0, stream>>>(flag, J, arena);

        int nF = GM * (FF / 128);             // 384
        int nD64 = GM * (DD / 64);            // 192
        int nQKV = GM * (3 * DD / 128);       // 288
        int nV = GM * (VV / 128);             // 4000

        for (int l = 0; l < LL; ++l) {
            size_t oB = (size_t)l * DD, oB1 = (size_t)l * FF;
            const u16* WqT = arena + O_WQ + l * SZ_D2;
            const u16* WkT = arena + O_WK + l * SZ_D2;
            const u16* WvT = arena + O_WV + l * SZ_D2;
            const u16* WoT = arena + O_WO + l * SZ_D2;
            const u16* W1T = arena + O_W1 + l * SZ_DF;
            const u16* W2T = arena + O_W2 + l * SZ_DF;

            ln_kernel<<<MR, blk, 0, stream>>>(flag, x, ln1_g, oB, ln1_b, oB, hbuf);
            aqkv_kernel<<<nQKV, blk, 0, stream>>>(
                flag, hbuf, WqT, WkT, WvT, bq, bk, bv, oB, qb, kb, vb);
            fattn_kernel<<<dim3(SS / 64, HH, BB), blk, 0, stream>>>(qb, kb, vb, hbuf);
            agemm_kernel<2, false, true, 0><<<nD64, blk, 0, stream>>>(
                flag, hbuf, WoT, bo, oB, x, x, DD, DD, GM);
            ln_kernel<<<MR, blk, 0, stream>>>(flag, x, ln2_g, oB, ln2_b, oB, hbuf);
            agemm_kernel<4, true, false, 1><<<nF, blk, 0, stream>>>(
                flag, hbuf, W1T, b1, oB1, nullptr, ffb, FF, DD, GM);
            agemm_kernel<2, false, true, 0><<<nD64, blk, 0, stream>>>(
                flag, ffb, W2T, b2, oB, x, x, DD, FF, GM);
        }

        ln_kernel<<<MR, blk, 0, stream>>>(flag, x, lnf_g, 0, lnf_b, 0, hbuf);
        agemm_kernel<4, false, false, 2><<<nV, blk, 0, stream>>>(
            flag, hbuf, arena + O_FC, fc_b, 0, nullptr, d_out, VV, DD, GM);
    } else {
        // fallback: on-the-fly weight path (round-2 proven)
        int nD = GM * (DD / 128);
        int nQKV = GM * (3 * DD / 128);
        int nF = GM * (FF / 128);
        int nV = GM * (VV / 128);
        for (int l = 0; l < LL; ++l) {
            size_t oW  = (size_t)l * DD * DD, oB  = (size_t)l * DD;
            size_t oW1 = (size_t)l * DD * FF, oB1 = (size_t)l * FF;
            size_t oW2 = (size_t)l * FF * DD;
            ln_kernel<<<MR, blk, 0, stream>>>(flag, x, ln1_g, oB, ln1_b, oB, hbuf);
            qkv_kernel<<<nQKV, blk, 0, stream>>>(
                flag, hbuf, Wq, Wk, Wv, oW, bq, bk, bv, oB, qb, kb, vb, DD);
            fattn_kernel<<<dim3(SS / 64, HH, BB), blk, 0, stream>>>(qb, kb, vb, hbuf);
            mgemm_kernel<false, true, 0><<<nD, blk, 0, stream>>>(
                flag, hbuf, Wo, oW, bo, oB, x, x, DD, DD, GM);
            ln_kernel<<<MR, blk, 0, stream>>>(flag, x, ln2_g, oB, ln2_b, oB, hbuf);
            mgemm_kernel<true, false, 1><<<nF, blk, 0, stream>>>(
                flag, hbuf, W1, oW1, b1, oB1, nullptr, ffb, FF, DD, GM);
            mgemm_kernel<false, true, 0><<<nD, blk, 0, stream>>>(
                flag, ffb, W2, oW2, b2, oB, x, x, DD, FF, GM);
        }
        ln_kernel<<<MR, blk, 0, stream>>>(flag, x, lnf_g, 0, lnf_b, 0, hbuf);
        mgemm_kernel<false, false, 2><<<nV, blk, 0, stream>>>(
            flag, hbuf, fc_W, 0, fc_b, 0, nullptr, d_out, VV, DD, GM);
    }
}